// Round 20
// baseline (64.962 us; speedup 1.0000x reference)
//
#include <hip/hip_runtime.h>

#define NB   8
#define ND   64
#define NP   1024
#define KDIM 128
#define HID  256
#define OUTD 256
#define CSC  2.885390081777927f   // 2*log2(e)
#define PSTR 520                  // sred plane stride (mod 32 = 8)

typedef __attribute__((ext_vector_type(8))) short  bf16x8;
typedef __attribute__((ext_vector_type(4))) float  f32x4;

// E-trick: sigma = rcp(fma(Ed,Ep,1)); tanh = 1-2*sigma. EhpT transposed.
// R20: DEFERRED NORMALIZATION -- accumulate unnormalized num = sum_j(-2e^s)sig
// and den = sum_j e^s; divide per-row in k_reduce. Softmax no longer couples a
// full j-row to one block -> j split into 4 quarters -> grid 1024 x 512thr =
// 4 independent blocks/CU (32 waves). R16-R19's single-block-per-CU had no
// TLP to cover barriers/load latency (compiler sinks prefetch; VGPR 36-44).

__device__ __forceinline__ ushort f2bf(float f) {
    unsigned u = __float_as_uint(f);
    return (ushort)((u + 0x7FFFu + ((u >> 16) & 1u)) >> 16);
}

// K0: cast X -> bf16 (k-contig); W -> bf16 TRANSPOSED (WT[n][k]).
__global__ __launch_bounds__(256) void k_cast(
    const float* __restrict__ Xd, const float* __restrict__ Xp,
    const float* __restrict__ Wd, const float* __restrict__ Wa,
    const float* __restrict__ Wp, const float* __restrict__ Wb,
    ushort* __restrict__ Xdbf, ushort* __restrict__ Xpbf,
    ushort* __restrict__ WdT, ushort* __restrict__ WaT,
    ushort* __restrict__ WpT, ushort* __restrict__ WbT) {
    int blk = blockIdx.x, t = threadIdx.x;
    if (blk < 1024) {
        size_t i = ((size_t)blk << 10) + ((size_t)t << 2);
        float4 v = *(const float4*)(Xp + i);
        ushort4 o; o.x = f2bf(v.x); o.y = f2bf(v.y); o.z = f2bf(v.z); o.w = f2bf(v.w);
        *(ushort4*)(Xpbf + i) = o;
    } else if (blk < 1088) {
        size_t i = ((size_t)(blk - 1024) << 10) + ((size_t)t << 2);
        float4 v = *(const float4*)(Xd + i);
        ushort4 o; o.x = f2bf(v.x); o.y = f2bf(v.y); o.z = f2bf(v.z); o.w = f2bf(v.w);
        *(ushort4*)(Xdbf + i) = o;
    } else {
        int r = blk - 1088, mat = r >> 5;
        const float* W = (mat == 0) ? Wd : (mat == 1) ? Wa : (mat == 2) ? Wp : Wb;
        ushort* WT = (mat == 0) ? WdT : (mat == 1) ? WaT : (mat == 2) ? WpT : WbT;
        int o0 = ((r & 31) << 10) + (t << 2);
        int n = o0 >> 7, k0 = o0 & 127;
        ushort4 o;
        o.x = f2bf(W[(k0 + 0) * HID + n]);
        o.y = f2bf(W[(k0 + 1) * HID + n]);
        o.z = f2bf(W[(k0 + 2) * HID + n]);
        o.w = f2bf(W[(k0 + 3) * HID + n]);
        *(ushort4*)(WT + o0) = o;
    }
}

// K1: MFMA projection + fused exp2 (verified absmax 0.0625).
__global__ __launch_bounds__(256) void k_proj_mfma(
    const ushort* __restrict__ Xpbf, const ushort* __restrict__ Xdbf,
    const ushort* __restrict__ WdT, const ushort* __restrict__ WaT,
    const ushort* __restrict__ WpT, const ushort* __restrict__ WbT,
    float* __restrict__ Ehd, float* __restrict__ Efd,
    float* __restrict__ EhpT, float* __restrict__ Efp) {
    int blk = blockIdx.x, t = threadIdx.x;
    const ushort *A, *B;
    float* out; size_t obase; int ostride, am0, bn0;
    if (blk < 512) {
        int mt = blk >> 2, nt = blk & 3;
        A = Xpbf; am0 = mt * 64; B = WbT; bn0 = nt * 64;
        out = Efp; obase = (size_t)am0 * HID + bn0; ostride = HID;
    } else if (blk < 1024) {
        int r = blk - 512, b = r >> 6, rr = r & 63;
        int mt = rr >> 4, nt = rr & 15;
        A = WpT; am0 = mt * 64;
        B = Xpbf + (size_t)b * NP * KDIM; bn0 = nt * 64;
        out = EhpT; obase = ((size_t)(b * 256 + am0)) * NP + bn0; ostride = NP;
    } else if (blk < 1056) {
        int r = blk - 1024; int mt = r >> 2, nt = r & 3;
        A = Xdbf; am0 = mt * 64; B = WdT; bn0 = nt * 64;
        out = Ehd; obase = (size_t)am0 * HID + bn0; ostride = HID;
    } else {
        int r = blk - 1056; int mt = r >> 2, nt = r & 3;
        A = Xdbf; am0 = mt * 64; B = WaT; bn0 = nt * 64;
        out = Efd; obase = (size_t)am0 * HID + bn0; ostride = HID;
    }
    int l = t & 63, w = t >> 6;
    int wm = (w >> 1) << 5, wn = (w & 1) << 5;
    int lr = l & 15, lk = (l >> 4) << 3;
    const ushort* Ab = A + (size_t)(am0 + wm + lr) * KDIM + lk;
    const ushort* Bb = B + (size_t)(bn0 + wn + lr) * KDIM + lk;

    bf16x8 af[2][4], bfr[2][4];
#pragma unroll
    for (int f = 0; f < 2; ++f)
#pragma unroll
        for (int ks = 0; ks < 4; ++ks) {
            af[f][ks]  = *(const bf16x8*)(Ab + (size_t)(f << 4) * KDIM + (ks << 5));
            bfr[f][ks] = *(const bf16x8*)(Bb + (size_t)(f << 4) * KDIM + (ks << 5));
        }

    f32x4 acc[2][2];
#pragma unroll
    for (int mf = 0; mf < 2; ++mf)
#pragma unroll
        for (int nf = 0; nf < 2; ++nf) acc[mf][nf] = (f32x4){0.f, 0.f, 0.f, 0.f};
#pragma unroll
    for (int ks = 0; ks < 4; ++ks)
#pragma unroll
        for (int mf = 0; mf < 2; ++mf)
#pragma unroll
            for (int nf = 0; nf < 2; ++nf)
                acc[mf][nf] = __builtin_amdgcn_mfma_f32_16x16x32_bf16(
                    af[mf][ks], bfr[nf][ks], acc[mf][nf], 0, 0, 0);

#pragma unroll
    for (int mf = 0; mf < 2; ++mf)
#pragma unroll
        for (int nf = 0; nf < 2; ++nf)
#pragma unroll
            for (int r = 0; r < 4; ++r) {
                int m = wm + (mf << 4) + ((l >> 4) << 2) + r;
                int n = wn + (nf << 4) + (l & 15);
                out[obase + (size_t)m * ostride + n] =
                    __builtin_amdgcn_exp2f(acc[mf][nf][r] * CSC);
            }
}

// K2: FUSED scores+exp+facc (unnormalized). 2 i-rows x 256-j-quarter per
// block. grid = 1024 (b=blk&7, pair=(blk>>3)&31, jh=blk>>8), 512 threads,
// 4 blocks/CU.
// P1: jq=t&63 (4 j), hq=t>>6 (32 h); 8 evals per float4 EhpT load.
// P2 (t<256): reduce 8 hq, u = exp2(s*log2e); a2[j] = (-2u0,-2u1); den.
// P3: oq=t&63 (4 o), jg=t>>6 (32 j); num partials -> planes -> global.
__global__ __launch_bounds__(512, 8) void k_fused(
    const float* __restrict__ Ehd, const float* __restrict__ EhpT,
    const float* __restrict__ Efd, const float* __restrict__ Efp,
    const float* __restrict__ wsc, float* __restrict__ num,
    float* __restrict__ den) {
    int blk = blockIdx.x;
    int b = blk & 7, pair = (blk >> 3) & 31, jh = blk >> 8;
    int row0 = b * ND + pair * 2;
    int t = threadIdx.x;

    __shared__ float2 hrow[256];         // 2 KB
    __shared__ float  w2s[256];          // 1 KB
    __shared__ float2 a2[256];           // 2 KB  (-2*u for row0,row1)
    __shared__ float  sred[8 * PSTR];    // 16.6 KB
    __shared__ float  wsum0[4], wsum1[4];

    if (t < 256) {
        hrow[t] = make_float2(Ehd[((size_t)row0 << 8) + t],
                              Ehd[((size_t)(row0 + 1) << 8) + t]);
        w2s[t] = -2.0f * wsc[t];
    }
    __syncthreads();

    // ---- phase 1: shifted scores, 256 j x 256 h split 8 ways over h ----
    {
        int jq = t & 63, hq = t >> 6;    // hq 0..7 -> 32 h each
        const float* pB = EhpT + ((size_t)((b << 8) + (hq << 5))) * NP
                        + (jh << 8) + (jq << 2);
        float a00 = 0, a01 = 0, a02 = 0, a03 = 0;
        float a10 = 0, a11 = 0, a12 = 0, a13 = 0;
        for (int hh = 0; hh < 32; ++hh) {
            int h = (hq << 5) + hh;
            float2 hv = hrow[h];
            float wv = w2s[h];
            float4 p = *(const float4*)(pB + (size_t)hh * NP);
            a00 = fmaf(wv, __builtin_amdgcn_rcpf(fmaf(hv.x, p.x, 1.f)), a00);
            a01 = fmaf(wv, __builtin_amdgcn_rcpf(fmaf(hv.x, p.y, 1.f)), a01);
            a02 = fmaf(wv, __builtin_amdgcn_rcpf(fmaf(hv.x, p.z, 1.f)), a02);
            a03 = fmaf(wv, __builtin_amdgcn_rcpf(fmaf(hv.x, p.w, 1.f)), a03);
            a10 = fmaf(wv, __builtin_amdgcn_rcpf(fmaf(hv.y, p.x, 1.f)), a10);
            a11 = fmaf(wv, __builtin_amdgcn_rcpf(fmaf(hv.y, p.y, 1.f)), a11);
            a12 = fmaf(wv, __builtin_amdgcn_rcpf(fmaf(hv.y, p.z, 1.f)), a12);
            a13 = fmaf(wv, __builtin_amdgcn_rcpf(fmaf(hv.y, p.w, 1.f)), a13);
        }
        int base = (hq << 6) + jq;
        sred[0 * PSTR + base] = a00;  sred[1 * PSTR + base] = a01;
        sred[2 * PSTR + base] = a02;  sred[3 * PSTR + base] = a03;
        sred[4 * PSTR + base] = a10;  sred[5 * PSTR + base] = a11;
        sred[6 * PSTR + base] = a12;  sred[7 * PSTR + base] = a13;
    }
    __syncthreads();

    // ---- phase 2: u = e^s (unnormalized), den partial ----
    if (t < 256) {
        int jq2 = t >> 2, joff = t & 3;
        const float* p0 = sred + joff * PSTR + jq2;
        const float* p1 = sred + (4 + joff) * PSTR + jq2;
        float sc0 = 0.f, sc1 = 0.f;
#pragma unroll
        for (int hq = 0; hq < 8; ++hq) {
            sc0 += p0[hq << 6];
            sc1 += p1[hq << 6];
        }
        const float L2E = 1.4426950408889634f;
        float u0 = __builtin_amdgcn_exp2f(sc0 * L2E);
        float u1 = __builtin_amdgcn_exp2f(sc1 * L2E);
        a2[t] = make_float2(-2.f * u0, -2.f * u1);
        float s0 = u0, s1 = u1;
#pragma unroll
        for (int off = 32; off > 0; off >>= 1) {
            s0 += __shfl_xor(s0, off, 64);
            s1 += __shfl_xor(s1, off, 64);
        }
        if ((t & 63) == 0) { wsum0[t >> 6] = s0; wsum1[t >> 6] = s1; }
    }
    __syncthreads();
    if (t == 0) {
        den[((size_t)row0 << 2) + jh] =
            (wsum0[0] + wsum0[1]) + (wsum0[2] + wsum0[3]);
        den[((size_t)(row0 + 1) << 2) + jh] =
            (wsum1[0] + wsum1[1]) + (wsum1[2] + wsum1[3]);
    }

    // ---- phase 3: num partials over this j-quarter ----
    {
        int oq = t & 63, jg = t >> 6;    // jg 0..7 -> 32 j each
        int o0 = oq << 2;
        float4 fd0 = *(const float4*)(Efd + ((size_t)row0 << 8) + o0);
        float4 fd1 = *(const float4*)(Efd + ((size_t)(row0 + 1) << 8) + o0);
        const float* fpB = Efp + ((size_t)(b * NP + (jh << 8) + (jg << 5)) << 8) + o0;
        float b00 = 0, b01 = 0, b02 = 0, b03 = 0;
        float b10 = 0, b11 = 0, b12 = 0, b13 = 0;
        for (int jj = 0; jj < 32; ++jj) {
            float4 f = *(const float4*)(fpB + ((size_t)jj << 8));
            float2 av = a2[(jg << 5) + jj];
            b00 = fmaf(av.x, __builtin_amdgcn_rcpf(fmaf(fd0.x, f.x, 1.f)), b00);
            b01 = fmaf(av.x, __builtin_amdgcn_rcpf(fmaf(fd0.y, f.y, 1.f)), b01);
            b02 = fmaf(av.x, __builtin_amdgcn_rcpf(fmaf(fd0.z, f.z, 1.f)), b02);
            b03 = fmaf(av.x, __builtin_amdgcn_rcpf(fmaf(fd0.w, f.w, 1.f)), b03);
            b10 = fmaf(av.y, __builtin_amdgcn_rcpf(fmaf(fd1.x, f.x, 1.f)), b10);
            b11 = fmaf(av.y, __builtin_amdgcn_rcpf(fmaf(fd1.y, f.y, 1.f)), b11);
            b12 = fmaf(av.y, __builtin_amdgcn_rcpf(fmaf(fd1.z, f.z, 1.f)), b12);
            b13 = fmaf(av.y, __builtin_amdgcn_rcpf(fmaf(fd1.w, f.w, 1.f)), b13);
        }
        __syncthreads();                 // sred reads (phase 2) done
        int base = (jg << 6) + oq;
        sred[0 * PSTR + base] = b00;  sred[1 * PSTR + base] = b01;
        sred[2 * PSTR + base] = b02;  sred[3 * PSTR + base] = b03;
        sred[4 * PSTR + base] = b10;  sred[5 * PSTR + base] = b11;
        sred[6 * PSTR + base] = b12;  sred[7 * PSTR + base] = b13;
    }
    __syncthreads();

    {
        int r = t >> 8, o = t & 255;     // r 0..1
        const float* pk = sred + ((r << 2) + (o & 3)) * PSTR + (o >> 2);
        float s = 0.f;
#pragma unroll
        for (int g = 0; g < 8; ++g) s += pk[g << 6];
        num[(((size_t)(row0 + r) << 2) + jh) * 256 + o] = s;
    }
}

// K3: out[b][o] = 64 + sum_i (sum_jh num) * rcp(sum_jh den). grid = 8.
__global__ __launch_bounds__(256) void k_reduce(
    const float* __restrict__ num, const float* __restrict__ den,
    float* __restrict__ out) {
    int b = blockIdx.x, t = threadIdx.x;
    float s = 64.0f;
    for (int i = 0; i < 64; ++i) {
        size_t row = (size_t)(b * 64 + i);
        float D = (den[(row << 2) + 0] + den[(row << 2) + 1]) +
                  (den[(row << 2) + 2] + den[(row << 2) + 3]);
        const float* nb = num + (row << 2) * 256 + t;
        float n = (nb[0] + nb[256]) + (nb[512] + nb[768]);
        s += n * __builtin_amdgcn_rcpf(D);
    }
    out[(b << 8) + t] = s;
}

extern "C" void kernel_launch(void* const* d_in, const int* in_sizes, int n_in,
                              void* d_out, int out_size, void* d_ws, size_t ws_size,
                              hipStream_t stream) {
    const float* Xd  = (const float*)d_in[0];
    const float* Xp  = (const float*)d_in[1];
    const float* Wd  = (const float*)d_in[2];
    const float* Wp  = (const float*)d_in[3];
    const float* Wa  = (const float*)d_in[4];
    const float* Wb  = (const float*)d_in[5];
    const float* wsc = (const float*)d_in[6];
    float* out = (float*)d_out;

    float* ws = (float*)d_ws;
    float* Ehd  = ws;                         // 131072 f
    float* Efd  = Ehd + NB * ND * HID;        // 131072 f
    float* EhpT = Efd + NB * ND * OUTD;       // 2097152 f
    float* Efp  = EhpT + NB * NP * HID;       // 2097152 f
    float* stage = Efp + NB * NP * OUTD;      // bf16 staging (622592 f)
    ushort* Xpbf = (ushort*)stage;
    ushort* Xdbf = Xpbf + NB * NP * KDIM;
    ushort* WdT  = Xdbf + 65536;
    ushort* WaT  = WdT + 32768;
    ushort* WpT  = WaT + 32768;
    ushort* WbT  = WpT + 32768;
    float* numb = stage + 622592;             // 524288 f (512 rows x 4 jh x 256)
    float* denb = numb + 524288;              // 2048 f

    k_cast     <<<1216, 256, 0, stream>>>(Xd, Xp, Wd, Wa, Wp, Wb,
                                          Xdbf, Xpbf, WdT, WaT, WpT, WbT);
    k_proj_mfma<<<1088, 256, 0, stream>>>(Xpbf, Xdbf, WdT, WaT, WpT, WbT,
                                          Ehd, Efd, EhpT, Efp);
    k_fused    <<<1024, 512, 0, stream>>>(Ehd, EhpT, Efd, Efp, wsc, numb, denb);
    k_reduce   <<<NB, 256, 0, stream>>>(numb, denb, out);
}

// Round 21
// 59.081 us; speedup vs baseline: 1.0995x; 1.0995x over previous
//
#include <hip/hip_runtime.h>

#define NB   8
#define ND   64
#define NP   1024
#define KDIM 128
#define HID  256
#define OUTD 256
#define CSC  2.885390081777927f   // 2*log2(e)
#define PSTR 1048                 // sred plane stride: !=0 mod 32

typedef __attribute__((ext_vector_type(8))) short  bf16x8;
typedef __attribute__((ext_vector_type(4))) float  f32x4;

// E-trick: sigma = rcp(fma(Ed,Ep,1)); tanh = 1-2*sigma. EhpT transposed.
// R21: k_fused converged to ~43us across 4 TLP/ILP structures (R16-R20) ->
// issue-bound on sigma math; rcp (8cy quarter-rate) is 2/3 of the 12cy/elem
// floor. Fix is algebraic: 4-way reciprocal batching (exact):
//   sum_i c_i/u_i = [t1*p34 + t2*p12] * rcp(p12*p34)
// -> 1 rcp per 4 sigma, 9cy/elem. Range-safe: P <= ~1e17 << fp32 max.

__device__ __forceinline__ ushort f2bf(float f) {
    unsigned u = __float_as_uint(f);
    return (ushort)((u + 0x7FFFu + ((u >> 16) & 1u)) >> 16);
}

// sum_{i=1..4} c_i/u_i added to acc, one rcp.
__device__ __forceinline__ float comb4(float u1, float u2, float u3, float u4,
                                       float c1, float c2, float c3, float c4,
                                       float acc) {
    float p12 = u1 * u2, p34 = u3 * u4;
    float P   = p12 * p34;
    float t1  = fmaf(c1, u2, c2 * u1);
    float t2  = fmaf(c3, u4, c4 * u3);
    float num = fmaf(t1, p34, t2 * p12);
    return fmaf(num, __builtin_amdgcn_rcpf(P), acc);
}

// K0: cast X -> bf16 (k-contig); W -> bf16 TRANSPOSED (WT[n][k]).
__global__ __launch_bounds__(256) void k_cast(
    const float* __restrict__ Xd, const float* __restrict__ Xp,
    const float* __restrict__ Wd, const float* __restrict__ Wa,
    const float* __restrict__ Wp, const float* __restrict__ Wb,
    ushort* __restrict__ Xdbf, ushort* __restrict__ Xpbf,
    ushort* __restrict__ WdT, ushort* __restrict__ WaT,
    ushort* __restrict__ WpT, ushort* __restrict__ WbT) {
    int blk = blockIdx.x, t = threadIdx.x;
    if (blk < 1024) {
        size_t i = ((size_t)blk << 10) + ((size_t)t << 2);
        float4 v = *(const float4*)(Xp + i);
        ushort4 o; o.x = f2bf(v.x); o.y = f2bf(v.y); o.z = f2bf(v.z); o.w = f2bf(v.w);
        *(ushort4*)(Xpbf + i) = o;
    } else if (blk < 1088) {
        size_t i = ((size_t)(blk - 1024) << 10) + ((size_t)t << 2);
        float4 v = *(const float4*)(Xd + i);
        ushort4 o; o.x = f2bf(v.x); o.y = f2bf(v.y); o.z = f2bf(v.z); o.w = f2bf(v.w);
        *(ushort4*)(Xdbf + i) = o;
    } else {
        int r = blk - 1088, mat = r >> 5;
        const float* W = (mat == 0) ? Wd : (mat == 1) ? Wa : (mat == 2) ? Wp : Wb;
        ushort* WT = (mat == 0) ? WdT : (mat == 1) ? WaT : (mat == 2) ? WpT : WbT;
        int o0 = ((r & 31) << 10) + (t << 2);
        int n = o0 >> 7, k0 = o0 & 127;
        ushort4 o;
        o.x = f2bf(W[(k0 + 0) * HID + n]);
        o.y = f2bf(W[(k0 + 1) * HID + n]);
        o.z = f2bf(W[(k0 + 2) * HID + n]);
        o.w = f2bf(W[(k0 + 3) * HID + n]);
        *(ushort4*)(WT + o0) = o;
    }
}

// K1: MFMA projection + fused exp2 (verified absmax 0.0625).
__global__ __launch_bounds__(256) void k_proj_mfma(
    const ushort* __restrict__ Xpbf, const ushort* __restrict__ Xdbf,
    const ushort* __restrict__ WdT, const ushort* __restrict__ WaT,
    const ushort* __restrict__ WpT, const ushort* __restrict__ WbT,
    float* __restrict__ Ehd, float* __restrict__ Efd,
    float* __restrict__ EhpT, float* __restrict__ Efp) {
    int blk = blockIdx.x, t = threadIdx.x;
    const ushort *A, *B;
    float* out; size_t obase; int ostride, am0, bn0;
    if (blk < 512) {
        int mt = blk >> 2, nt = blk & 3;
        A = Xpbf; am0 = mt * 64; B = WbT; bn0 = nt * 64;
        out = Efp; obase = (size_t)am0 * HID + bn0; ostride = HID;
    } else if (blk < 1024) {
        int r = blk - 512, b = r >> 6, rr = r & 63;
        int mt = rr >> 4, nt = rr & 15;
        A = WpT; am0 = mt * 64;
        B = Xpbf + (size_t)b * NP * KDIM; bn0 = nt * 64;
        out = EhpT; obase = ((size_t)(b * 256 + am0)) * NP + bn0; ostride = NP;
    } else if (blk < 1056) {
        int r = blk - 1024; int mt = r >> 2, nt = r & 3;
        A = Xdbf; am0 = mt * 64; B = WdT; bn0 = nt * 64;
        out = Ehd; obase = (size_t)am0 * HID + bn0; ostride = HID;
    } else {
        int r = blk - 1056; int mt = r >> 2, nt = r & 3;
        A = Xdbf; am0 = mt * 64; B = WaT; bn0 = nt * 64;
        out = Efd; obase = (size_t)am0 * HID + bn0; ostride = HID;
    }
    int l = t & 63, w = t >> 6;
    int wm = (w >> 1) << 5, wn = (w & 1) << 5;
    int lr = l & 15, lk = (l >> 4) << 3;
    const ushort* Ab = A + (size_t)(am0 + wm + lr) * KDIM + lk;
    const ushort* Bb = B + (size_t)(bn0 + wn + lr) * KDIM + lk;

    bf16x8 af[2][4], bfr[2][4];
#pragma unroll
    for (int f = 0; f < 2; ++f)
#pragma unroll
        for (int ks = 0; ks < 4; ++ks) {
            af[f][ks]  = *(const bf16x8*)(Ab + (size_t)(f << 4) * KDIM + (ks << 5));
            bfr[f][ks] = *(const bf16x8*)(Bb + (size_t)(f << 4) * KDIM + (ks << 5));
        }

    f32x4 acc[2][2];
#pragma unroll
    for (int mf = 0; mf < 2; ++mf)
#pragma unroll
        for (int nf = 0; nf < 2; ++nf) acc[mf][nf] = (f32x4){0.f, 0.f, 0.f, 0.f};
#pragma unroll
    for (int ks = 0; ks < 4; ++ks)
#pragma unroll
        for (int mf = 0; mf < 2; ++mf)
#pragma unroll
            for (int nf = 0; nf < 2; ++nf)
                acc[mf][nf] = __builtin_amdgcn_mfma_f32_16x16x32_bf16(
                    af[mf][ks], bfr[nf][ks], acc[mf][nf], 0, 0, 0);

#pragma unroll
    for (int mf = 0; mf < 2; ++mf)
#pragma unroll
        for (int nf = 0; nf < 2; ++nf)
#pragma unroll
            for (int r = 0; r < 4; ++r) {
                int m = wm + (mf << 4) + ((l >> 4) << 2) + r;
                int n = wn + (nf << 4) + (l & 15);
                out[obase + (size_t)m * ostride + n] =
                    __builtin_amdgcn_exp2f(acc[mf][nf][r] * CSC);
            }
}

// K2: FUSED scores+softmax+facc, 2 i-rows/block, grid 256, 1024 thr.
// Inner loops use 4-way reciprocal batching (comb4): 1 rcp per 4 sigma.
__global__ __launch_bounds__(1024, 4) void k_fused(
    const float* __restrict__ Ehd, const float* __restrict__ EhpT,
    const float* __restrict__ Efd, const float* __restrict__ Efp,
    const float* __restrict__ wsc, float* __restrict__ part) {
    int blk = blockIdx.x;
    int b = blk & 7, pair = blk >> 3;
    int row0 = b * ND + pair * 2;
    int t = threadIdx.x;

    __shared__ float2 hrow[256];
    __shared__ float  w2s[256];
    __shared__ float2 a2[1024];
    __shared__ float  sred[8 * PSTR];
    __shared__ float  wsum0[16], wsum1[16];

    if (t < 256) {
        hrow[t] = make_float2(Ehd[((size_t)row0 << 8) + t],
                              Ehd[((size_t)(row0 + 1) << 8) + t]);
        w2s[t] = -2.0f * wsc[t];
    }
    __syncthreads();

    // ---- phase 1: scores, 4 h combined per rcp ----
    {
        int jq = t & 255, hq = t >> 8;
        const float* pB = EhpT + ((size_t)((b << 8) + (hq << 6))) * NP + (jq << 2);
        float a00 = 0, a01 = 0, a02 = 0, a03 = 0;
        float a10 = 0, a11 = 0, a12 = 0, a13 = 0;
        for (int hg = 0; hg < 16; ++hg) {
            const float* pr = pB + (size_t)(hg << 2) * NP;
            float4 p0 = *(const float4*)(pr);
            float4 p1 = *(const float4*)(pr + NP);
            float4 p2 = *(const float4*)(pr + 2 * (size_t)NP);
            float4 p3 = *(const float4*)(pr + 3 * (size_t)NP);
            int h = (hq << 6) + (hg << 2);
            float2 h0 = hrow[h],     h1 = hrow[h + 1];
            float2 h2 = hrow[h + 2], h3 = hrow[h + 3];
            float w0 = w2s[h],     w1 = w2s[h + 1];
            float w2 = w2s[h + 2], w3 = w2s[h + 3];
            a00 = comb4(fmaf(h0.x, p0.x, 1.f), fmaf(h1.x, p1.x, 1.f),
                        fmaf(h2.x, p2.x, 1.f), fmaf(h3.x, p3.x, 1.f),
                        w0, w1, w2, w3, a00);
            a01 = comb4(fmaf(h0.x, p0.y, 1.f), fmaf(h1.x, p1.y, 1.f),
                        fmaf(h2.x, p2.y, 1.f), fmaf(h3.x, p3.y, 1.f),
                        w0, w1, w2, w3, a01);
            a02 = comb4(fmaf(h0.x, p0.z, 1.f), fmaf(h1.x, p1.z, 1.f),
                        fmaf(h2.x, p2.z, 1.f), fmaf(h3.x, p3.z, 1.f),
                        w0, w1, w2, w3, a02);
            a03 = comb4(fmaf(h0.x, p0.w, 1.f), fmaf(h1.x, p1.w, 1.f),
                        fmaf(h2.x, p2.w, 1.f), fmaf(h3.x, p3.w, 1.f),
                        w0, w1, w2, w3, a03);
            a10 = comb4(fmaf(h0.y, p0.x, 1.f), fmaf(h1.y, p1.x, 1.f),
                        fmaf(h2.y, p2.x, 1.f), fmaf(h3.y, p3.x, 1.f),
                        w0, w1, w2, w3, a10);
            a11 = comb4(fmaf(h0.y, p0.y, 1.f), fmaf(h1.y, p1.y, 1.f),
                        fmaf(h2.y, p2.y, 1.f), fmaf(h3.y, p3.y, 1.f),
                        w0, w1, w2, w3, a11);
            a12 = comb4(fmaf(h0.y, p0.z, 1.f), fmaf(h1.y, p1.z, 1.f),
                        fmaf(h2.y, p2.z, 1.f), fmaf(h3.y, p3.z, 1.f),
                        w0, w1, w2, w3, a12);
            a13 = comb4(fmaf(h0.y, p0.w, 1.f), fmaf(h1.y, p1.w, 1.f),
                        fmaf(h2.y, p2.w, 1.f), fmaf(h3.y, p3.w, 1.f),
                        w0, w1, w2, w3, a13);
        }
        int base = (hq << 8) + jq;
        sred[0 * PSTR + base] = a00;  sred[1 * PSTR + base] = a01;
        sred[2 * PSTR + base] = a02;  sred[3 * PSTR + base] = a03;
        sred[4 * PSTR + base] = a10;  sred[5 * PSTR + base] = a11;
        sred[6 * PSTR + base] = a12;  sred[7 * PSTR + base] = a13;
    }
    __syncthreads();

    // ---- phase 2: softmax (no max pass: |S| <= 2*sum|w| ~ 32, fp32-safe) ----
    {
        int jq2 = t >> 2, c = t & 3;
        const float* p0 = sred + c * PSTR + jq2;
        const float* p1 = sred + (4 + c) * PSTR + jq2;
        float sc0 = (p0[0] + p0[256]) + (p0[512] + p0[768]);
        float sc1 = (p1[0] + p1[256]) + (p1[512] + p1[768]);
        const float L2E = 1.4426950408889634f;
        float e0 = __builtin_amdgcn_exp2f(sc0 * L2E);
        float e1 = __builtin_amdgcn_exp2f(sc1 * L2E);
        float s0 = e0, s1 = e1;
#pragma unroll
        for (int off = 32; off > 0; off >>= 1) {
            s0 += __shfl_xor(s0, off, 64);
            s1 += __shfl_xor(s1, off, 64);
        }
        if ((t & 63) == 0) { wsum0[t >> 6] = s0; wsum1[t >> 6] = s1; }
        __syncthreads();
        float tot0 = 0.f, tot1 = 0.f;
#pragma unroll
        for (int w = 0; w < 16; ++w) { tot0 += wsum0[w]; tot1 += wsum1[w]; }
        float sn0 = -2.0f * __builtin_amdgcn_rcpf(tot0);
        float sn1 = -2.0f * __builtin_amdgcn_rcpf(tot1);
        a2[t] = make_float2(e0 * sn0, e1 * sn1);
    }
    __syncthreads();

    // ---- phase 3: facc, 4 j combined per rcp ----
    {
        int oq = t & 63, jg = t >> 6;
        int o0 = oq << 2;
        float4 fd0 = *(const float4*)(Efd + ((size_t)row0 << 8) + o0);
        float4 fd1 = *(const float4*)(Efd + ((size_t)(row0 + 1) << 8) + o0);
        const float* fpB = Efp + ((size_t)(b * NP + (jg << 6)) << 8) + o0;
        float b00 = 0, b01 = 0, b02 = 0, b03 = 0;
        float b10 = 0, b11 = 0, b12 = 0, b13 = 0;
        for (int g = 0; g < 16; ++g) {
            const float* fr = fpB + ((size_t)(g << 2) << 8);
            float4 f0 = *(const float4*)(fr);
            float4 f1 = *(const float4*)(fr + 256);
            float4 f2 = *(const float4*)(fr + 512);
            float4 f3 = *(const float4*)(fr + 768);
            int j0 = (jg << 6) + (g << 2);
            float2 A0 = a2[j0],     A1 = a2[j0 + 1];
            float2 A2v = a2[j0 + 2], A3 = a2[j0 + 3];
            b00 = comb4(fmaf(fd0.x, f0.x, 1.f), fmaf(fd0.x, f1.x, 1.f),
                        fmaf(fd0.x, f2.x, 1.f), fmaf(fd0.x, f3.x, 1.f),
                        A0.x, A1.x, A2v.x, A3.x, b00);
            b01 = comb4(fmaf(fd0.y, f0.y, 1.f), fmaf(fd0.y, f1.y, 1.f),
                        fmaf(fd0.y, f2.y, 1.f), fmaf(fd0.y, f3.y, 1.f),
                        A0.x, A1.x, A2v.x, A3.x, b01);
            b02 = comb4(fmaf(fd0.z, f0.z, 1.f), fmaf(fd0.z, f1.z, 1.f),
                        fmaf(fd0.z, f2.z, 1.f), fmaf(fd0.z, f3.z, 1.f),
                        A0.x, A1.x, A2v.x, A3.x, b02);
            b03 = comb4(fmaf(fd0.w, f0.w, 1.f), fmaf(fd0.w, f1.w, 1.f),
                        fmaf(fd0.w, f2.w, 1.f), fmaf(fd0.w, f3.w, 1.f),
                        A0.x, A1.x, A2v.x, A3.x, b03);
            b10 = comb4(fmaf(fd1.x, f0.x, 1.f), fmaf(fd1.x, f1.x, 1.f),
                        fmaf(fd1.x, f2.x, 1.f), fmaf(fd1.x, f3.x, 1.f),
                        A0.y, A1.y, A2v.y, A3.y, b10);
            b11 = comb4(fmaf(fd1.y, f0.y, 1.f), fmaf(fd1.y, f1.y, 1.f),
                        fmaf(fd1.y, f2.y, 1.f), fmaf(fd1.y, f3.y, 1.f),
                        A0.y, A1.y, A2v.y, A3.y, b11);
            b12 = comb4(fmaf(fd1.z, f0.z, 1.f), fmaf(fd1.z, f1.z, 1.f),
                        fmaf(fd1.z, f2.z, 1.f), fmaf(fd1.z, f3.z, 1.f),
                        A0.y, A1.y, A2v.y, A3.y, b12);
            b13 = comb4(fmaf(fd1.w, f0.w, 1.f), fmaf(fd1.w, f1.w, 1.f),
                        fmaf(fd1.w, f2.w, 1.f), fmaf(fd1.w, f3.w, 1.f),
                        A0.y, A1.y, A2v.y, A3.y, b13);
        }
        __syncthreads();                 // phase-2 sred reads done
        int base = (jg << 6) + oq;
        sred[0 * PSTR + base] = b00;  sred[1 * PSTR + base] = b01;
        sred[2 * PSTR + base] = b02;  sred[3 * PSTR + base] = b03;
        sred[4 * PSTR + base] = b10;  sred[5 * PSTR + base] = b11;
        sred[6 * PSTR + base] = b12;  sred[7 * PSTR + base] = b13;
    }
    __syncthreads();

    if (t < 512) {
        int r = t >> 8, o = t & 255;
        int oq2 = o >> 2, c2 = o & 3;
        const float* pk = sred + (r * 4 + c2) * PSTR + oq2;
        float s = 0.f;
#pragma unroll
        for (int g = 0; g < 16; ++g) s += pk[g << 6];
        part[((size_t)((b << 6) + (pair << 1) + r) << 8) + o] = s;
    }
}

// K3: out[b][o] = 64 + sum over 64 i-rows. grid = 8. part layout [b][i][o].
__global__ __launch_bounds__(256) void k_reduce(
    const float* __restrict__ part, float* __restrict__ out) {
    int b = blockIdx.x, t = threadIdx.x;
    float s = 64.0f;
#pragma unroll 8
    for (int i = 0; i < 64; ++i)
        s += part[((size_t)((b << 6) + i) << 8) + t];
    out[(b << 8) + t] = s;
}

extern "C" void kernel_launch(void* const* d_in, const int* in_sizes, int n_in,
                              void* d_out, int out_size, void* d_ws, size_t ws_size,
                              hipStream_t stream) {
    const float* Xd  = (const float*)d_in[0];
    const float* Xp  = (const float*)d_in[1];
    const float* Wd  = (const float*)d_in[2];
    const float* Wp  = (const float*)d_in[3];
    const float* Wa  = (const float*)d_in[4];
    const float* Wb  = (const float*)d_in[5];
    const float* wsc = (const float*)d_in[6];
    float* out = (float*)d_out;

    float* ws = (float*)d_ws;
    float* Ehd  = ws;
    float* Efd  = Ehd + NB * ND * HID;
    float* EhpT = Efd + NB * ND * OUTD;
    float* Efp  = EhpT + NB * NP * HID;
    float* stage = Efp + NB * NP * OUTD;
    ushort* Xpbf = (ushort*)stage;
    ushort* Xdbf = Xpbf + NB * NP * KDIM;
    ushort* WdT  = Xdbf + 65536;
    ushort* WaT  = WdT + 32768;
    ushort* WpT  = WaT + 32768;
    ushort* WbT  = WpT + 32768;
    float* part  = stage;

    k_cast     <<<1216, 256, 0, stream>>>(Xd, Xp, Wd, Wa, Wp, Wb,
                                          Xdbf, Xpbf, WdT, WaT, WpT, WbT);
    k_proj_mfma<<<1088, 256, 0, stream>>>(Xpbf, Xdbf, WdT, WaT, WpT, WbT,
                                          Ehd, Efd, EhpT, Efp);
    k_fused    <<<256, 1024, 0, stream>>>(Ehd, EhpT, Efd, Efp, wsc, part);
    k_reduce   <<<NB, 256, 0, stream>>>(part, out);
}